// Round 8
// baseline (263.756 us; speedup 1.0000x reference)
//
#include <hip/hip_runtime.h>
#include <stdint.h>

#define MDIM 4096
#define NDIM 4096
#define KDIM 4096
#define BM 256
#define BN 256
#define BKB 128            // K-bytes (int8 elems) per tile step
#define NT (KDIM / BKB)    // 32 K-tiles

typedef int i32x4 __attribute__((ext_vector_type(4)));

typedef __attribute__((address_space(1))) const void gv_t;
typedef __attribute__((address_space(3))) void lv_t;

#define BAR() do { asm volatile("" ::: "memory"); __builtin_amdgcn_s_barrier(); asm volatile("" ::: "memory"); } while (0)
// full LDS-read fence before a barrier: no wave may cross with ds_reads pending,
// because the phase after the barrier overwrites regions read in this phase.
#define LGKM0_BAR() do { asm volatile("s_waitcnt lgkmcnt(0)" ::: "memory"); BAR(); } while (0)

__device__ __forceinline__ int pack4(int a, int b, int c, int d) {
    return (a & 0xFF) | ((b & 0xFF) << 8) | ((c & 0xFF) << 16) | ((d & 0xFF) << 24);
}

__global__ void pack_x_kernel(const int* __restrict__ x, const int* __restrict__ zp_p,
                              int* __restrict__ out, int total4) {
    const int zp = zp_p[0];
    int i = blockIdx.x * blockDim.x + threadIdx.x;
    if (i < total4) {
        int4 a = ((const int4*)x)[i];
        out[i] = pack4(a.x - zp, a.y - zp, a.z - zp, a.w - zp);
    }
}

__global__ void pack_w_kernel(const int* __restrict__ w, int* __restrict__ out, int total4) {
    int i = blockIdx.x * blockDim.x + threadIdx.x;
    if (i < total4) {
        int4 a = ((const int4*)w)[i];
        out[i] = pack4(a.x, a.y, a.z, a.w);
    }
}

// 256x256-tile i8 GEMM, 4-phase/K-tile counted-vmcnt schedule (m201 port).
// Race-freedom invariants (round-6 post-mortem):
//  (1) every phase-end barrier is preceded by s_waitcnt lgkmcnt(0) — no wave
//      crosses with pending LDS reads, so a later phase may overwrite any
//      already-read region;
//  (2) stage writes are ordered only by counted vmcnt at p3: steady state has
//      12 loads outstanding there; vmcnt(4) ⇒ tile tt+1 fully landed, only
//      (tt+2, A0/A1) in flight. vmcnt(0) at tt >= NT-2 drains the tail.
// Stage schedule: p0->(t+1,B0), p1->(t+1,B1), p2->(t+2,A0), p3->(t+2,A1).
__global__ __launch_bounds__(512, 2)
void gemm_i8_8ph(const char* __restrict__ A8, const char* __restrict__ B8,
                 const float* __restrict__ bias,
                 const float* __restrict__ xs_p, const float* __restrict__ ws_p,
                 const float* __restrict__ os_p, const int* __restrict__ ozp_p,
                 int* __restrict__ out) {
    __shared__ char lds[131072];   // A: [2][32KB] @0, B: [2][32KB] @64KB

    const int t = threadIdx.x;
    const int lane = t & 63;
    const int wave = t >> 6;       // 0..7
    const int wr = wave >> 2;      // 2 M-waves: rows wr*128..+127
    const int wc = wave & 3;       // 4 N-waves: cols wc*64..+63

    // XCD-aware bijective swizzle: nwg=256, 256%8==0
    int wg = blockIdx.x;
    int swz = (wg & 7) * (256 / 8) + (wg >> 3);
    const long brow = (long)(swz >> 4) * BM;
    const long bcol = (long)(swz & 15) * BN;

    i32x4 acc[8][4] = {};

    // -------- loop-invariant addressing, hoisted --------
    int aoff[8][2], boff[4][2];
    #pragma unroll
    for (int mi = 0; mi < 8; ++mi) {
        int row = wr * 128 + mi * 16 + (lane & 15);
        #pragma unroll
        for (int kk = 0; kk < 2; ++kk) {
            int ls = kk * 4 + (lane >> 4);
            aoff[mi][kk] = row * BKB + ((ls ^ (row & 7)) * 16);
        }
    }
    #pragma unroll
    for (int ni = 0; ni < 4; ++ni) {
        int row = wc * 64 + ni * 16 + (lane & 15);
        #pragma unroll
        for (int kk = 0; kk < 2; ++kk) {
            int ls = kk * 4 + (lane >> 4);
            boff[ni][kk] = 65536 + row * BKB + ((ls ^ (row & 7)) * 16);
        }
    }
    // stage bases: half h (0,1 = A rows 0-127/128-255; 2,3 = B same), j = 0,1
    const char* sbase[4][2];
    int ldsoff[4][2];
    #pragma unroll
    for (int h = 0; h < 4; ++h) {
        const char* src = (h < 2) ? A8 : B8;
        long rc = (h < 2) ? brow : bcol;
        #pragma unroll
        for (int j = 0; j < 2; ++j) {
            int chunk = (h & 1) * 1024 + t + j * 512;   // 16B chunk in tile
            int row = chunk >> 3, slot = chunk & 7;
            sbase[h][j] = src + (rc + row) * KDIM + ((slot ^ (row & 7)) * 16);
            ldsoff[h][j] = ((h < 2) ? 0 : 65536) + chunk * 16;
        }
    }

#define STAGE(tt_, h_) do { \
    if ((tt_) < NT) { \
        int dd_ = ((tt_) & 1) * 32768; \
        __builtin_amdgcn_global_load_lds((gv_t*)(sbase[h_][0] + (long)(tt_) * BKB), \
                                         (lv_t*)(lds + dd_ + ldsoff[h_][0]), 16, 0, 0); \
        __builtin_amdgcn_global_load_lds((gv_t*)(sbase[h_][1] + (long)(tt_) * BKB), \
                                         (lv_t*)(lds + dd_ + ldsoff[h_][1]), 16, 0, 0); \
    } } while (0)

#define MFMA_Q(MLO, NLO) do { \
    __builtin_amdgcn_s_setprio(1); \
    _Pragma("unroll") \
    for (int mi = MLO; mi < MLO + 4; ++mi) \
        _Pragma("unroll") \
        for (int ni = NLO; ni < NLO + 2; ++ni) \
            _Pragma("unroll") \
            for (int kk = 0; kk < 2; ++kk) \
                acc[mi][ni] = __builtin_amdgcn_mfma_i32_16x16x64_i8(af[mi][kk], bf[ni][kk], acc[mi][ni], 0, 0, 0); \
    __builtin_amdgcn_s_setprio(0); \
} while (0)

    // prologue: tile0 fully, tile1 A-halves (B-halves staged in p0/p1 of t0)
    STAGE(0, 0); STAGE(0, 1); STAGE(0, 2); STAGE(0, 3);
    STAGE(1, 0); STAGE(1, 1);
    asm volatile("s_waitcnt vmcnt(4)" ::: "memory");   // tile 0 landed
    BAR();

    i32x4 af[8][2], bf[4][2];

    #pragma unroll 2
    for (int tt = 0; tt < NT; ++tt) {
        const int dpar = (tt & 1) * 32768;

        // ---- p0: read af[0..3], bf[0..1]; quadrant (M0,N0) ----
        #pragma unroll
        for (int mi = 0; mi < 4; ++mi)
            #pragma unroll
            for (int kk = 0; kk < 2; ++kk)
                af[mi][kk] = *(const i32x4*)(lds + dpar + aoff[mi][kk]);
        #pragma unroll
        for (int ni = 0; ni < 2; ++ni)
            #pragma unroll
            for (int kk = 0; kk < 2; ++kk)
                bf[ni][kk] = *(const i32x4*)(lds + dpar + boff[ni][kk]);
        STAGE(tt + 1, 2);
        BAR();
        MFMA_Q(0, 0);
        LGKM0_BAR();

        // ---- p1: read af[4..7]; quadrant (M1,N0) ----
        #pragma unroll
        for (int mi = 4; mi < 8; ++mi)
            #pragma unroll
            for (int kk = 0; kk < 2; ++kk)
                af[mi][kk] = *(const i32x4*)(lds + dpar + aoff[mi][kk]);
        STAGE(tt + 1, 3);
        BAR();
        MFMA_Q(4, 0);
        LGKM0_BAR();   // all A-parity-d reads done before p2 stages (tt+2,A0)

        // ---- p2: read bf[2..3]; quadrant (M0,N1) ----
        #pragma unroll
        for (int ni = 2; ni < 4; ++ni)
            #pragma unroll
            for (int kk = 0; kk < 2; ++kk)
                bf[ni][kk] = *(const i32x4*)(lds + dpar + boff[ni][kk]);
        STAGE(tt + 2, 0);
        BAR();
        MFMA_Q(0, 2);
        LGKM0_BAR();   // all B-parity-d reads done before tile tt+1 p0 stages B

        // ---- p3: quadrant (M1,N1); per-tile vmcnt ----
        STAGE(tt + 2, 1);
        BAR();
        MFMA_Q(4, 2);
        if (tt >= NT - 2)      asm volatile("s_waitcnt vmcnt(0)" ::: "memory");
        else                   asm volatile("s_waitcnt vmcnt(4)" ::: "memory");
        BAR();                 // next tile's data now visible to all waves
    }
#undef STAGE
#undef MFMA_Q

    // epilogue: dequant + bias, requant round-half-even, clip, int32 store
    const float scale = xs_p[0] * ws_p[0];
    const float os = os_p[0];
    const int ozp = ozp_p[0];
    #pragma unroll
    for (int mi = 0; mi < 8; ++mi) {
        long row0 = brow + wr * 128 + mi * 16 + (lane >> 4) * 4;
        #pragma unroll
        for (int ni = 0; ni < 4; ++ni) {
            long col = bcol + wc * 64 + ni * 16 + (lane & 15);
            float bv = bias[col];
            #pragma unroll
            for (int r = 0; r < 4; ++r) {
                float y = (float)acc[mi][ni][r] * scale + bv;
                int q = (int)rintf(y / os) + ozp;
                q = q < 0 ? 0 : (q > 255 ? 255 : q);
                out[(row0 + r) * NDIM + col] = q;
            }
        }
    }
}

// insurance fallback if workspace is too small (should not trigger)
__global__ void naive_gemm_kernel(const int* __restrict__ x, const int* __restrict__ w,
                                  const float* __restrict__ bias,
                                  const float* __restrict__ xs_p, const int* __restrict__ xzp_p,
                                  const float* __restrict__ ws_p, const float* __restrict__ os_p,
                                  const int* __restrict__ ozp_p, int* __restrict__ out) {
    long idx = (long)blockIdx.x * blockDim.x + threadIdx.x;
    if (idx >= (long)MDIM * NDIM) return;
    int m = idx >> 12, n = idx & (NDIM - 1);
    const int4* xr = (const int4*)(x + (long)m * KDIM);
    const int4* wv = (const int4*)(w + (long)n * KDIM);
    const int zp = xzp_p[0];
    int acc = 0;
    for (int k = 0; k < KDIM / 4; ++k) {
        int4 a = xr[k], b = wv[k];
        acc += (a.x - zp) * b.x + (a.y - zp) * b.y + (a.z - zp) * b.z + (a.w - zp) * b.w;
    }
    float y = (float)acc * (xs_p[0] * ws_p[0]) + bias[n];
    int q = (int)rintf(y / os_p[0]) + ozp_p[0];
    out[idx] = q < 0 ? 0 : (q > 255 ? 255 : q);
}

extern "C" void kernel_launch(void* const* d_in, const int* in_sizes, int n_in,
                              void* d_out, int out_size, void* d_ws, size_t ws_size,
                              hipStream_t stream) {
    const int*   x_q  = (const int*)d_in[0];
    const int*   w_q  = (const int*)d_in[1];
    const float* bias = (const float*)d_in[2];
    const float* xs   = (const float*)d_in[3];
    const int*   xzp  = (const int*)d_in[4];
    const float* wsc  = (const float*)d_in[5];
    const float* osc  = (const float*)d_in[6];
    const int*   ozp  = (const int*)d_in[7];
    int* out = (int*)d_out;

    const size_t need = 2UL * MDIM * KDIM;  // 32 MB packed int8
    if (ws_size >= need) {
        char* A8 = (char*)d_ws;
        char* B8 = A8 + (size_t)MDIM * KDIM;
        const int total4 = MDIM * KDIM / 4;
        pack_x_kernel<<<total4 / 256, 256, 0, stream>>>(x_q, xzp, (int*)A8, total4);
        pack_w_kernel<<<total4 / 256, 256, 0, stream>>>(w_q, (int*)B8, total4);
        gemm_i8_8ph<<<(MDIM / BM) * (NDIM / BN), 512, 0, stream>>>(
            A8, B8, bias, xs, wsc, osc, ozp, out);
    } else {
        long total = (long)MDIM * NDIM;
        naive_gemm_kernel<<<(total + 255) / 256, 256, 0, stream>>>(
            x_q, w_q, bias, xs, xzp, wsc, osc, ozp, out);
    }
}